// Round 7
// baseline (201.558 us; speedup 1.0000x reference)
//
#include <hip/hip_runtime.h>
#include <hip/hip_bf16.h>
#include <stdint.h>

// SSMBlock: x -> silu(x Wg^T) -> s = xg Wsp^T -> scan(decay) -> out = states WcT^T + xg W2^T + b_out
// R6 GEMM "gemm_l2b": A (streaming, no reuse) -> LDS via global_load_lds double-buffer
// (8KB bufs, 1 barrier per BK=64); B (W, 512KB, L2-hot) -> direct global->VGPR with a
// static 2-slot prefetch ring. LDS reads: 2 per 8 MFMAs. 16KB LDS -> 4 blocks/CU.

typedef __bf16 bf16_t;
typedef bf16_t bf16x8 __attribute__((ext_vector_type(8)));
typedef bf16_t bf16x4 __attribute__((ext_vector_type(4)));
typedef float  f32x4  __attribute__((ext_vector_type(4)));

static __device__ __forceinline__ void async_copy16(bf16_t* lds, const bf16_t* g) {
    __builtin_amdgcn_global_load_lds((const __attribute__((address_space(1))) void*)g,
                                     (__attribute__((address_space(3))) void*)lds, 16, 0, 0);
}

// Block 256 thr / 4 waves (2x2). Block tile 64(M) x 128(N); wave tile 32x64.
// K is processed in NT steps of 64 (NT=8 single GEMM, NT=16 concat dual GEMM:
// t<8 -> A0/W0, t>=8 -> A1/W1, k' = (t&7)*64).
// LDS Abuf[2][kcomb(8)][row(64)][8] (8KB per buf): gll dest linear in lane order;
// ds_read_b128 per 16-lane group = contiguous 256B -> 0 bank conflicts.
// b-frags: global, lane(lr,kc) reads W[col n0+wc*64+j*16+lr][k + kc*8], i.e. 16 rows
// x 64B contiguous per instr (proven-coalesced pattern, L2-resident).
// MODE: 0 = f32 out (+bias), 1 = bf16 out (+bias), 2 = silu -> bf16 (+bias)
template <int MODE>
__global__ __launch_bounds__(256, 4) void gemm_l2b(
    const bf16_t* __restrict__ A0, const bf16_t* __restrict__ W0,
    const bf16_t* __restrict__ A1, const bf16_t* __restrict__ W1,
    const float* __restrict__ bias, void* __restrict__ outp,
    int M, int Nw, int NT)
{
    __shared__ bf16_t Abuf[2][8 * 64 * 8];   // 2 x 8 KB
    const int tid = threadIdx.x;
    const int tN = Nw >> 7;
    const int m0 = (blockIdx.x / tN) << 6, n0 = (blockIdx.x % tN) << 7;
    const int l = tid & 63, w = tid >> 6;
    const int wr = w >> 1, wc = w & 1;
    const int lr = l & 15, kc = l >> 4;

    float bv[4];
    #pragma unroll
    for (int j = 0; j < 4; ++j)
        bv[j] = bias ? bias[n0 + wc * 64 + j * 16 + lr] : 0.f;

    f32x4 acc[2][4];
    const f32x4 z = {0.f, 0.f, 0.f, 0.f};
    #pragma unroll
    for (int i = 0; i < 2; ++i)
        #pragma unroll
        for (int j = 0; j < 4; ++j) acc[i][j] = z;

    const size_t bcol = (size_t)(n0 + wc * 64 + lr) * 512;  // + j*16*512 per frag

    // stage A chunk for step tt into Abuf[tt&1]: 512 chunks of 16B, 2/thread.
    // chunk c = j*256 + tid -> kcomb = c>>6, row = c&63; lanes contiguous per wave.
    auto stageA = [&](int tt) {
        const bf16_t* __restrict__ Asrc = (tt < 8) ? A0 : A1;
        const int kk = (tt & 7) << 6;
        bf16_t* buf = Abuf[tt & 1];
        #pragma unroll
        for (int j = 0; j < 2; ++j) {
            const int c = j * 256 + tid;
            async_copy16(buf + (j * 256 + w * 64) * 8,
                         Asrc + (size_t)(m0 + (c & 63)) * 512 + kk + ((c >> 6) << 3));
        }
    };
    // load 4 b-frags for (tt, s) into dst
    auto loadB = [&](int tt, int s, bf16x8* dst) {
        const bf16_t* __restrict__ Wsrc = (tt < 8) ? W0 : W1;
        const int kk = ((tt & 7) << 6) + (s << 5) + (kc << 3);
        #pragma unroll
        for (int j = 0; j < 4; ++j)
            dst[j] = *(const bf16x8*)(Wsrc + bcol + (size_t)j * 16 * 512 + kk);
    };

    bf16x8 bpf0[4], bpf1[4];
    loadB(0, 0, bpf0);
    stageA(0);
    __syncthreads();                       // Abuf[0] ready (drains gll)

    for (int t = 0; t < NT; ++t) {
        const bf16_t* __restrict__ buf = Abuf[t & 1];
        // ---- sub-step s=0 ----
        loadB(t, 1, bpf1);                 // prefetch s=1 (slot 1; s=0 uses slot 0)
        bf16x8 a0[2];
        #pragma unroll
        for (int i = 0; i < 2; ++i)
            a0[i] = *(const bf16x8*)(buf + ((kc * 64) + wr * 32 + i * 16 + lr) * 8);
        #pragma unroll
        for (int i = 0; i < 2; ++i)
            #pragma unroll
            for (int j = 0; j < 4; ++j)
                acc[i][j] = __builtin_amdgcn_mfma_f32_16x16x32_bf16(a0[i], bpf0[j], acc[i][j], 0, 0, 0);
        // ---- prefetch next step; gll staged LAST so b-waits don't drain it ----
        if (t + 1 < NT) {
            loadB(t + 1, 0, bpf0);         // slot 0 (s=0 consumers already done)
            stageA(t + 1);                 // -> Abuf[(t+1)&1], drained by sync below
        }
        // ---- sub-step s=1 ----
        bf16x8 a1[2];
        #pragma unroll
        for (int i = 0; i < 2; ++i)
            a1[i] = *(const bf16x8*)(buf + ((4 + kc) * 64 + wr * 32 + i * 16 + lr) * 8);
        #pragma unroll
        for (int i = 0; i < 2; ++i)
            #pragma unroll
            for (int j = 0; j < 4; ++j)
                acc[i][j] = __builtin_amdgcn_mfma_f32_16x16x32_bf16(a1[i], bpf1[j], acc[i][j], 0, 0, 0);
        __syncthreads();                   // Abuf[(t+1)&1] ready; reads of buf done
    }

    // C/D layout: col = lane&15, row = (lane>>4)*4 + reg
    float*  outF = (float*)outp;
    bf16_t* outB = (bf16_t*)outp;
    #pragma unroll
    for (int i = 0; i < 2; ++i) {
        const int row = m0 + wr * 32 + i * 16 + kc * 4;
        #pragma unroll
        for (int j = 0; j < 4; ++j) {
            const int col = n0 + wc * 64 + j * 16 + lr;
            #pragma unroll
            for (int r = 0; r < 4; ++r) {
                float v = acc[i][j][r] + bv[j];
                size_t idx = (size_t)(row + r) * Nw + col;
                if (MODE == 0)      outF[idx] = v;
                else if (MODE == 1) outB[idx] = (bf16_t)v;
                else { outB[idx] = (bf16_t)(v / (1.f + __expf(-v))); }
            }
        }
    }
}

// fused prep: x->bf16 (all 8192 blocks), weight prep (blocks<1024), decay (blocks<128)
__global__ void prep_all(const float4* __restrict__ x, bf16x4* __restrict__ xb,
                         const float* __restrict__ Wg, const float* __restrict__ Wsp,
                         const float* __restrict__ Wo, const float* __restrict__ Dp,
                         bf16_t* __restrict__ Wg_bf, bf16_t* __restrict__ Wsp_bf,
                         bf16_t* __restrict__ Wo_bf, bf16_t* __restrict__ W2_bf,
                         const float* __restrict__ A_log, float* __restrict__ decay)
{
    const int blk = blockIdx.x, tid = threadIdx.x;
    {   // x -> bf16, 4 floats/thread
        int i = blk * 256 + tid;
        float4 v = x[i];
        bf16x4 o;
        o[0] = (bf16_t)v.x; o[1] = (bf16_t)v.y; o[2] = (bf16_t)v.z; o[3] = (bf16_t)v.w;
        xb[i] = o;
    }
    if (blk < 1024) {
        int i = blk * 256 + tid;          // 512*512 elements
        Wg_bf[i]  = (bf16_t)Wg[i];
        Wsp_bf[i] = (bf16_t)Wsp[i];
        float wo  = Wo[i];
        Wo_bf[i]  = (bf16_t)wo;
        W2_bf[i]  = (bf16_t)(wo * Dp[i & 511]);   // W2[d',d] = W_out[d',d]*D[d]
    }
    if (blk < 128) {
        int d = blk * 4 + (tid >> 6);     // one wave per row of A_log
        int ll = tid & 63;
        const float* row = A_log + (size_t)d * 512;
        float s = 0.f;
        for (int k = ll; k < 512; k += 64) s += expf(row[k]);
        #pragma unroll
        for (int off = 32; off > 0; off >>= 1) s += __shfl_down(s, off);
        if (ll == 0) decay[d] = expf(-s * (1.f / 512.f));  // exp(mean(-exp(A_log)))
    }
}

// ---- chunked scan: S=4096 -> 64 chunks x 64 steps, per (b,n) lane ----
__global__ void scan_partial(const bf16_t* __restrict__ s, const float* __restrict__ decay,
                             float* __restrict__ carry)
{
    int g = blockIdx.x * 256 + threadIdx.x;       // B*N*64 = 131072
    int n = g & 511, ch = (g >> 9) & 63, b = g >> 15;
    float dec = decay[n];
    const bf16_t* sp = s + (size_t)(b * 4096 + ch * 64) * 512 + n;
    float st = 0.f;
    #pragma unroll 8
    for (int i = 0; i < 64; ++i) st = st * dec + (float)sp[(size_t)i * 512];
    carry[(size_t)(b * 64 + ch) * 512 + n] = st;
}

__global__ void scan_carry(const float* __restrict__ carry, const float* __restrict__ decay,
                           const float* __restrict__ state0,
                           float* __restrict__ exc, float* __restrict__ state_f)
{
    int g = blockIdx.x * 256 + threadIdx.x;       // B*N = 2048
    int n = g & 511, b = g >> 9;
    float dec = decay[n];
    float d64 = dec;
    #pragma unroll
    for (int t = 0; t < 6; ++t) d64 *= d64;       // dec^64 via squaring
    float st = state0[g];
    for (int ch = 0; ch < 64; ++ch) {
        size_t idx = (size_t)(b * 64 + ch) * 512 + n;
        exc[idx] = st;                             // exclusive carry-in per chunk
        st = st * d64 + carry[idx];
    }
    state_f[g] = st;                               // final state -> d_out tail
}

__global__ void scan_final(const bf16_t* __restrict__ s, const float* __restrict__ decay,
                           const float* __restrict__ exc, bf16_t* __restrict__ states)
{
    int g = blockIdx.x * 256 + threadIdx.x;       // B*N*64
    int n = g & 511, ch = (g >> 9) & 63, b = g >> 15;
    float dec = decay[n];
    float st = exc[(size_t)(b * 64 + ch) * 512 + n];
    size_t base = (size_t)(b * 4096 + ch * 64) * 512 + n;
    #pragma unroll 8
    for (int i = 0; i < 64; ++i) {
        st = st * dec + (float)s[base + (size_t)i * 512];
        states[base + (size_t)i * 512] = (bf16_t)st;
    }
}

extern "C" void kernel_launch(void* const* d_in, const int* in_sizes, int n_in,
                              void* d_out, int out_size, void* d_ws, size_t ws_size,
                              hipStream_t stream)
{
    const float* x      = (const float*)d_in[0];
    const float* state0 = (const float*)d_in[1];
    const float* W_gate = (const float*)d_in[2];
    const float* b_gate = (const float*)d_in[3];
    const float* W_sp   = (const float*)d_in[4];
    const float* b_sp   = (const float*)d_in[5];
    const float* W_out  = (const float*)d_in[6];
    const float* b_out  = (const float*)d_in[7];
    const float* A_log  = (const float*)d_in[8];
    const float* D_par  = (const float*)d_in[9];
    float* out = (float*)d_out;

    // workspace layout (~51.5 MB)
    char* ws = (char*)d_ws;
    bf16_t* x_bf   = (bf16_t*)ws;                     // 16 MB, reused for states
    bf16_t* states = x_bf;
    bf16_t* xg_bf  = (bf16_t*)(ws + (16u << 20));     // 16 MB
    bf16_t* s_bf   = (bf16_t*)(ws + (32u << 20));     // 16 MB
    bf16_t* Wg_bf  = (bf16_t*)(ws + (48u << 20));     // 5 x 512 KB weights
    bf16_t* Wsp_bf = Wg_bf + 262144;
    bf16_t* Wo_bf  = Wg_bf + 2 * 262144;
    bf16_t* W2_bf  = Wg_bf + 3 * 262144;
    bf16_t* WcT_bf = Wg_bf + 4 * 262144;
    float*  carry  = (float*)(Wg_bf + 5 * 262144);    // 512 KB
    float*  exc    = carry + 131072;                  // 512 KB
    float*  decay  = exc + 131072;                    // 2 KB

    prep_all<<<dim3(8192), dim3(256), 0, stream>>>(
        (const float4*)x, (bf16x4*)x_bf, W_gate, W_sp, W_out, D_par,
        Wg_bf, Wsp_bf, Wo_bf, W2_bf, A_log, decay);

    // WcT[d',n] = sum_d W_out[d',d] * W_sp[n,d]   (M=512 -> grid 8x4 = 32)
    gemm_l2b<1><<<dim3(32), dim3(256), 0, stream>>>(
        Wo_bf, Wsp_bf, Wo_bf, Wsp_bf, (const float*)nullptr, (void*)WcT_bf,
        512, 512, 8);
    // xg = silu(x W_gate^T + b_gate)   (grid 256x4 = 1024 -> 4 blocks/CU)
    gemm_l2b<2><<<dim3(1024), dim3(256), 0, stream>>>(
        x_bf, Wg_bf, x_bf, Wg_bf, b_gate, (void*)xg_bf, 16384, 512, 8);
    // s = xg W_sp^T + b_sp
    gemm_l2b<1><<<dim3(1024), dim3(256), 0, stream>>>(
        xg_bf, Wsp_bf, xg_bf, Wsp_bf, b_sp, (void*)s_bf, 16384, 512, 8);

    scan_partial<<<dim3(512), dim3(256), 0, stream>>>(s_bf, decay, carry);
    scan_carry<<<dim3(8), dim3(256), 0, stream>>>(carry, decay, state0, exc, out + 8388608);
    scan_final<<<dim3(512), dim3(256), 0, stream>>>(s_bf, decay, exc, states);

    // out = states WcT^T + xg W2^T + b_out   (concat-K: NT=16)
    gemm_l2b<0><<<dim3(1024), dim3(256), 0, stream>>>(
        states, WcT_bf, xg_bf, W2_bf, b_out, (void*)out, 16384, 512, 16);
}